// Round 9
// baseline (424.116 us; speedup 1.0000x reference)
//
#include <hip/hip_runtime.h>

typedef __attribute__((ext_vector_type(8))) short short8;
typedef __attribute__((ext_vector_type(4))) short short4_t;
typedef __attribute__((ext_vector_type(4))) float f32x4;

#define MFMA_B16(a, b, c) __builtin_amdgcn_mfma_f32_16x16x32_bf16((a), (b), (c), 0, 0, 0)

__device__ __forceinline__ unsigned short f2bf(float x) {
    unsigned u = __builtin_bit_cast(unsigned, x);
    u = (u + 0x7FFFu + ((u >> 16) & 1u)) >> 16;
    return (unsigned short)u;
}

__device__ __forceinline__ void load16_lds(const void* g, void* l) {
    __builtin_amdgcn_global_load_lds(
        (const __attribute__((address_space(1))) unsigned int*)g,
        (__attribute__((address_space(3))) unsigned int*)l, 16, 0, 0);
}

// ---------------- multi-tensor fp32 -> bf16 convert (8 elems/thread) --------
__global__ __launch_bounds__(256) void cvt5(
    const float* s0, unsigned short* d0, int n0,
    const float* s1, unsigned short* d1, int n1,
    const float* s2, unsigned short* d2, int n2,
    const float* s3, unsigned short* d3, int n3,
    const float* s4, unsigned short* d4, int n4)
{
    const float* s; unsigned short* d; int n;
    switch (blockIdx.y) {
        case 0:  s = s0; d = d0; n = n0; break;
        case 1:  s = s1; d = d1; n = n1; break;
        case 2:  s = s2; d = d2; n = n2; break;
        case 3:  s = s3; d = d3; n = n3; break;
        default: s = s4; d = d4; n = n4; break;
    }
    const int i = blockIdx.x * 256 + threadIdx.x;
    if (i < n) {
        const float* p = s + (size_t)i * 8;
        f32x4 x0 = *(const f32x4*)p;
        f32x4 x1 = *(const f32x4*)(p + 4);
        short8 r;
#pragma unroll
        for (int j = 0; j < 4; ++j) r[j] = (short)f2bf(x0[j]);
#pragma unroll
        for (int j = 0; j < 4; ++j) r[j + 4] = (short)f2bf(x1[j]);
        *(short8*)(d + (size_t)i * 8) = r;
    }
}

// ---------------- NT GEMM: BM=64 x BN=128 tile, global_load_lds staging -----
// 4 waves: wm = wave>>1 (32 m-rows), wn = wave&1 (64 n-cols); 2x4 MFMA each.
// Grid: (N/128, M/64, nz). mode: 0 = bf16 row-major, 1 = V^T per-head
// [b][h][64][2048], 2 = fp32 row-major.
struct GemmDesc {
    const unsigned short* A;
    const unsigned short* W;
    const float* bias;
    void* out;
    float scale;
    int mode;
};

__global__ __launch_bounds__(256) void gemm64(GemmDesc g0, GemmDesc g1, GemmDesc g2)
{
    constexpr int K = 1024;
    __shared__ union {
        struct { short A[64 * 32]; short W[128 * 32]; } st;
        short Lt[128 * 72];
    } sm;

    const GemmDesc g = (blockIdx.z == 0) ? g0 : (blockIdx.z == 1 ? g1 : g2);
    const int t = threadIdx.x;
    const int lane = t & 63, wave = t >> 6;
    const int lanelo = lane & 15, quad = lane >> 4;
    const int wm = wave >> 1, wn = wave & 1;
    const int bn = blockIdx.x * 128;
    const int bm = blockIdx.y * 64;

    f32x4 acc[2][4] = {};

    const int r0 = t >> 2, c0 = (t & 3) * 8;
    const unsigned short* Ag = g.A + (size_t)(bm + r0) * K + c0;
    const unsigned short* Wg = g.W + (size_t)(bn + r0) * K + c0;
    short* ldsA = sm.st.A + wave * 512;   // wave-uniform base; lanes at +lane*16B
    short* ldsW = sm.st.W + wave * 512;

    for (int k0 = 0; k0 < K; k0 += 32) {
        __syncthreads();
        load16_lds(Ag + k0, ldsA);
        load16_lds(Wg + k0, ldsW);
        load16_lds(Wg + (size_t)64 * K + k0, ldsW + 2048);
        __syncthreads();

        short8 af[2], wf[4];
#pragma unroll
        for (int mt = 0; mt < 2; ++mt)
            af[mt] = *(const short8*)&sm.st.A[(wm * 32 + mt * 16 + lanelo) * 32 + quad * 8];
#pragma unroll
        for (int nt = 0; nt < 4; ++nt)
            wf[nt] = *(const short8*)&sm.st.W[(wn * 64 + nt * 16 + lanelo) * 32 + quad * 8];
#pragma unroll
        for (int mt = 0; mt < 2; ++mt)
#pragma unroll
            for (int nt = 0; nt < 4; ++nt)
                acc[mt][nt] = MFMA_B16(af[mt], wf[nt], acc[mt][nt]);
    }

    if (g.mode != 1) {
#pragma unroll
        for (int mt = 0; mt < 2; ++mt) {
#pragma unroll
            for (int nt = 0; nt < 4; ++nt) {
                const int col = bn + wn * 64 + nt * 16 + lanelo;
                const float bs = g.bias[col];
#pragma unroll
                for (int r = 0; r < 4; ++r) {
                    const int row = bm + wm * 32 + mt * 16 + quad * 4 + r;
                    const float val = (acc[mt][nt][r] + bs) * g.scale;
                    if (g.mode == 2)
                        ((float*)g.out)[(size_t)row * K + col] = val;
                    else
                        ((unsigned short*)g.out)[(size_t)row * K + col] = f2bf(val);
                }
            }
        }
    } else {
        // V^T epilogue: transpose 64(s) x 128(d = 2 heads) via LDS union
        __syncthreads();
#pragma unroll
        for (int mt = 0; mt < 2; ++mt) {
#pragma unroll
            for (int nt = 0; nt < 4; ++nt) {
                const int nl = wn * 64 + nt * 16 + lanelo;   // d-local 0..127
                const float bs = g.bias[bn + nl];
                short4_t pk;
#pragma unroll
                for (int r = 0; r < 4; ++r) pk[r] = (short)f2bf(acc[mt][nt][r] + bs);
                *(short4_t*)&sm.Lt[nl * 72 + wm * 32 + mt * 16 + quad * 4] = pk;
            }
        }
        __syncthreads();
        const int dl = t >> 1;            // 0..127
        const int sb = (t & 1) * 32;      // s half
        const int bb = bm >> 11;          // batch
        const int s0 = bm & 2047;
        const int hb = bb * 16 + ((bn + dl) >> 6);
        const int dd = (bn + dl) & 63;
        unsigned short* dst = (unsigned short*)g.out +
            ((size_t)hb * 64 + dd) * 2048 + s0 + sb;
#pragma unroll
        for (int j = 0; j < 4; ++j)
            *(short8*)(dst + j * 8) = *(const short8*)&sm.Lt[dl * 72 + sb + j * 8];
    }
}

// ---------------- flash attention: 1 wave/block, 16 q-rows, no barriers ----
// Grid 128x32 = 4096 waves = 4/SIMD (VGPR-matched). Wave-private P in LDS;
// DS ops in-order per wave => wave_barrier (compiler fence) suffices; no
// vmcnt(0) drain ever => K/V register prefetch stays in flight.
// Q pre-scaled by 0.125*log2(e); no-max softmax; P truncated to bf16 with l
// summed from the SAME truncated values (bias cancels in the O/l ratio).
__global__ __launch_bounds__(64) void attn_flash(
    const unsigned short* __restrict__ Qs,
    const unsigned short* __restrict__ Ks,
    const unsigned short* __restrict__ Vt,
    unsigned short* __restrict__ Op)
{
    constexpr int S = 2048, D = 1024;
    __shared__ short Pl[16 * 72];   // wave-private P tile [16 q][64 key]

    const int lane   = threadIdx.x;       // 0..63
    const int lanelo = lane & 15;
    const int quad   = lane >> 4;
    const int qt = blockIdx.x;            // 0..127 (16 q-rows per block)
    const int b  = blockIdx.y >> 4;
    const int h  = blockIdx.y & 15;
    const size_t base = (size_t)b * S * D + (size_t)h * 64;
    const unsigned short* Vh = Vt + (size_t)(b * 16 + h) * 64 * S;

    short8 aq[2];
#pragma unroll
    for (int ks = 0; ks < 2; ++ks)
        aq[ks] = *(const short8*)(Qs + base +
            (size_t)(qt * 16 + lanelo) * D + ks * 32 + quad * 8);

    f32x4 oacc[4] = {};
    f32x4 lac = {};

    const unsigned short* kp = Ks + base + (size_t)lanelo * D + quad * 8;
    const unsigned short* vp = Vh + (size_t)lanelo * S + quad * 8;

    short8 kfr[2][4], vfr[2][4];
#pragma unroll
    for (int ks = 0; ks < 2; ++ks)
#pragma unroll
        for (int nt = 0; nt < 4; ++nt) {
            kfr[ks][nt] = *(const short8*)(kp + (size_t)(nt * 16) * D + ks * 32);
            vfr[ks][nt] = *(const short8*)(vp + (size_t)(nt * 16) * S + ks * 32);
        }

    for (int kt = 0; kt < 32; ++kt) {
        // S' = Q K^T (exp2 domain)
        f32x4 sv[4] = {};
#pragma unroll
        for (int ks = 0; ks < 2; ++ks)
#pragma unroll
            for (int nt = 0; nt < 4; ++nt)
                sv[nt] = MFMA_B16(aq[ks], kfr[ks][nt], sv[nt]);

        // prefetch next K tile (never drained by a barrier)
        if (kt < 31) {
            const unsigned short* kn = kp + (size_t)((kt + 1) * 64) * D;
#pragma unroll
            for (int ks = 0; ks < 2; ++ks)
#pragma unroll
                for (int nt = 0; nt < 4; ++nt)
                    kfr[ks][nt] = *(const short8*)(kn + (size_t)(nt * 16) * D + ks * 32);
        }

        // p = exp2(s); truncate to bf16 for BOTH the P store and the l sum
#pragma unroll
        for (int r = 0; r < 4; ++r) {
            const int prow = (quad * 4 + r) * 72;
#pragma unroll
            for (int nt = 0; nt < 4; ++nt) {
                const float p = exp2f(sv[nt][r]);
                const unsigned u = __builtin_bit_cast(unsigned, p) & 0xFFFF0000u;
                lac[r] += __builtin_bit_cast(float, u);
                Pl[prow + nt * 16 + lanelo] = (short)(u >> 16);
            }
        }

        __builtin_amdgcn_wave_barrier();   // DS order: P writes before reads

        // O += P @ V
#pragma unroll
        for (int ks = 0; ks < 2; ++ks) {
            short8 ap = *(const short8*)&Pl[lanelo * 72 + ks * 32 + quad * 8];
#pragma unroll
            for (int nt = 0; nt < 4; ++nt)
                oacc[nt] = MFMA_B16(ap, vfr[ks][nt], oacc[nt]);
        }

        __builtin_amdgcn_wave_barrier();   // DS order: reads before next writes

        // prefetch next V tile
        if (kt < 31) {
            const unsigned short* vn = vp + (kt + 1) * 64;
#pragma unroll
            for (int ks = 0; ks < 2; ++ks)
#pragma unroll
                for (int nt = 0; nt < 4; ++nt)
                    vfr[ks][nt] = *(const short8*)(vn + (size_t)(nt * 16) * S + ks * 32);
        }
    }

#pragma unroll
    for (int r = 0; r < 4; ++r) {
        float l = lac[r];
        l += __shfl_xor(l, 1);
        l += __shfl_xor(l, 2);
        l += __shfl_xor(l, 4);
        l += __shfl_xor(l, 8);
        const float inv = 1.0f / l;
        const int row = qt * 16 + quad * 4 + r;
#pragma unroll
        for (int nt = 0; nt < 4; ++nt)
            Op[base + (size_t)row * D + nt * 16 + lanelo] = f2bf(oacc[nt][r] * inv);
    }
}

extern "C" void kernel_launch(void* const* d_in, const int* in_sizes, int n_in,
                              void* d_out, int out_size, void* d_ws, size_t ws_size,
                              hipStream_t stream) {
    const float* q   = (const float*)d_in[0];
    const float* k   = (const float*)d_in[1];
    const float* v   = (const float*)d_in[2];
    const float* W_q = (const float*)d_in[3];
    const float* b_q = (const float*)d_in[4];
    const float* W_k = (const float*)d_in[5];
    const float* b_k = (const float*)d_in[6];
    const float* W_v = (const float*)d_in[7];
    const float* b_v = (const float*)d_in[8];
    const float* W_o = (const float*)d_in[9];
    const float* b_o = (const float*)d_in[10];

    constexpr size_t M4 = (size_t)4 * 1024 * 1024;
    constexpr size_t M1 = (size_t)1024 * 1024;

    unsigned short* ob   = (unsigned short*)d_out;
    unsigned short* qb16 = ob;                 // [0,4M)
    unsigned short* wq16 = ob + M4;            // [4M,5M)
    unsigned short* wk16 = ob + M4 + M1;       // [5M,6M)
    unsigned short* wv16 = ob + M4 + 2 * M1;   // [6M,7M)
    unsigned short* d0   = (unsigned short*)d_in[0];
    unsigned short* d1   = (unsigned short*)d_in[1];
    unsigned short* d2   = (unsigned short*)d_in[2];
    unsigned short* kb16 = d0;                 // k bf16 (q fp32 dead after cvtA)
    unsigned short* vb16 = d0 + M4;            // v bf16
    unsigned short* wo16 = d0;                 // W_o bf16 (over kb16, after QKV gemm)
    unsigned short* Qst  = d1;                 // Q stage
    unsigned short* Kst  = d1 + M4;            // K stage
    unsigned short* Vts  = d2;                 // V^T stage
    unsigned short* Ob16 = d2 + M4;            // O stage
    float*          outp = (float*)d_out;

    const dim3 blk(256, 1, 1);
    const int n4 = (int)(M4 / 8), n1 = (int)(M1 / 8);
    const float QSCALE = 0.18033688f;    // 0.125 * log2(e)

    cvt5<<<dim3(2048, 4, 1), blk, 0, stream>>>(
        q, qb16, n4,  W_q, wq16, n1,  W_k, wk16, n1,  W_v, wv16, n1,
        (const float*)nullptr, (unsigned short*)nullptr, 0);
    cvt5<<<dim3(2048, 2, 1), blk, 0, stream>>>(
        k, kb16, n4,  v, vb16, n4, nullptr, nullptr, 0,
        nullptr, nullptr, 0, nullptr, nullptr, 0);
    {
        GemmDesc gq{qb16, wq16, b_q, Qst, QSCALE, 0};
        GemmDesc gk{kb16, wk16, b_k, Kst, 1.0f, 0};
        GemmDesc gv{vb16, wv16, b_v, Vts, 1.0f, 1};
        gemm64<<<dim3(8, 64, 3), blk, 0, stream>>>(gq, gk, gv);
    }
    cvt5<<<dim3(512, 1, 1), blk, 0, stream>>>(
        W_o, wo16, n1, nullptr, nullptr, 0, nullptr, nullptr, 0,
        nullptr, nullptr, 0, nullptr, nullptr, 0);
    attn_flash<<<dim3(128, 32, 1), dim3(64, 1, 1), 0, stream>>>(Qst, Kst, Vts, Ob16);
    {
        GemmDesc go{Ob16, wo16, b_o, outp, 1.0f, 2};
        gemm64<<<dim3(8, 64, 1), blk, 0, stream>>>(go, go, go);
    }
}